// Round 9
// baseline (255.300 us; speedup 1.0000x reference)
//
#include <hip/hip_runtime.h>
#include <math.h>

#define BB 2
#define LL 4096
#define DD 1024
#define NORD 2
#define NEMB 3
#define NFO 64
#define KW 3
#define TAPS 64    // window=exp(-0.5*n) -> e^-32 at n=64; exact truncation in f32

typedef __attribute__((ext_vector_type(8))) short bf16x8;
typedef __attribute__((ext_vector_type(4))) float f32x4;

__device__ __forceinline__ void gl_lds16(const void* g, void* s) {
    __builtin_amdgcn_global_load_lds(
        (const __attribute__((address_space(1))) void*)g,
        (__attribute__((address_space(3))) void*)s, 16, 0, 0);
}

__device__ __forceinline__ float bf2f(unsigned short u) {
    union { unsigned int i; float f; } v; v.i = ((unsigned int)u) << 16; return v.f;
}
__device__ __forceinline__ unsigned short f2bf(float f) {
    union { float f; unsigned int i; } v; v.f = f;
    unsigned int r = v.i + 0x7FFF + ((v.i >> 16) & 1);   // round-nearest-even
    return (unsigned short)(r >> 16);
}

__device__ __forceinline__ float gelu_exact(float x) {
    return 0.5f * x * (1.0f + erff(x * 0.70710678118654752440f));
}

// ---------------------------------------------------------------------------
// Fused prep kernel (unchanged): cvt + 4 transposes + filter
// ---------------------------------------------------------------------------
__device__ void wtrans_dev(const float* __restrict__ src, unsigned short* __restrict__ dst,
                           int K, int N, int bx, int by, int tid)
{
    __shared__ float t[32][33];
    const int n0 = bx * 32;
    const int k0 = by * 32;
    const int r = tid >> 5;
    const int c = tid & 31;
    #pragma unroll
    for (int p = 0; p < 4; ++p)
        t[r + p * 8][c] = src[(size_t)(k0 + r + p * 8) * N + n0 + c];
    __syncthreads();
    #pragma unroll
    for (int p = 0; p < 4; ++p)
        dst[(size_t)(n0 + r + p * 8) * K + k0 + c] = f2bf(t[c][r + p * 8]);
}

__global__ __launch_bounds__(256) void prep_kernel(
    const float* __restrict__ x, unsigned short* __restrict__ xb,
    const float* __restrict__ ipw, unsigned short* __restrict__ ipwT,
    const float* __restrict__ gw, unsigned short* __restrict__ gw0T, unsigned short* __restrict__ gw1T,
    const float* __restrict__ opw, unsigned short* __restrict__ opwT,
    const float* __restrict__ freqs, const float* __restrict__ w1, const float* __restrict__ b1,
    const float* __restrict__ w2, const float* __restrict__ b2,
    const float* __restrict__ w3, const float* __restrict__ b3,
    const float* __restrict__ decay, float* __restrict__ hout)
{
    const int bid = blockIdx.x;
    const int tid = threadIdx.x;

    if (bid < 4096) {
        size_t i = ((size_t)bid * 256 + tid) * 8;
        float4 a = *(const float4*)(x + i);
        float4 b = *(const float4*)(x + i + 4);
        bf16x8 o;
        o[0] = (short)f2bf(a.x); o[1] = (short)f2bf(a.y); o[2] = (short)f2bf(a.z); o[3] = (short)f2bf(a.w);
        o[4] = (short)f2bf(b.x); o[5] = (short)f2bf(b.y); o[6] = (short)f2bf(b.z); o[7] = (short)f2bf(b.w);
        *(bf16x8*)(xb + i) = o;
        return;
    }
    if (bid < 7168) { int q = bid - 4096; wtrans_dev(ipw, ipwT, 1024, 3072, q % 96, q / 96, tid); return; }
    if (bid < 8192) { int q = bid - 7168; wtrans_dev(gw, gw0T, 1024, 1024, q % 32, q / 32, tid); return; }
    if (bid < 9216) { int q = bid - 8192; wtrans_dev(gw + (size_t)1024 * 1024, gw1T, 1024, 1024, q % 32, q / 32, tid); return; }
    if (bid < 10240) { int q = bid - 9216; wtrans_dev(opw, opwT, 1024, 1024, q % 32, q / 32, tid); return; }

    const int q = bid - 10240;
    const int i = q / TAPS;
    const int n = q % TAPS;
    const float t = (float)n / (float)(LL - 1);

    __shared__ float s1[NFO];
    __shared__ float s2[NFO];

    if (tid < NFO) {
        float enc[7];
        const float* fr = freqs + i * NEMB;
        const float c2pi = 6.28318530717958647692f;
        #pragma unroll
        for (int e = 0; e < 3; ++e) {
            float a = c2pi * fr[e] * t;
            enc[e]     = sinf(a);
            enc[e + 3] = cosf(a);
        }
        enc[6] = t;
        const float* w = w1 + i * 7 * NFO;
        float acc = b1[i * NFO + tid];
        #pragma unroll
        for (int e = 0; e < 7; ++e) acc += enc[e] * w[e * NFO + tid];
        s1[tid] = gelu_exact(acc);
    }
    __syncthreads();
    if (tid < NFO) {
        const float* w = w2 + i * NFO * NFO;
        float acc = b2[i * NFO + tid];
        #pragma unroll 8
        for (int g = 0; g < NFO; ++g) acc += s1[g] * w[g * NFO + tid];
        s2[tid] = gelu_exact(acc);
    }
    __syncthreads();

    const int c0 = tid * 4;
    const float* w = w3 + (size_t)i * NFO * DD + c0;
    float4 acc = *(const float4*)(b3 + (size_t)i * DD + c0);
    #pragma unroll 8
    for (int g = 0; g < NFO; ++g) {
        float hg = s2[g];
        float4 wv = *(const float4*)(w + (size_t)g * DD);
        acc.x += hg * wv.x; acc.y += hg * wv.y; acc.z += hg * wv.z; acc.w += hg * wv.w;
    }
    float4 dc = *(const float4*)(decay + (size_t)i * DD + c0);
    float tl = t * (float)LL;
    acc.x *= expf(-fabsf(dc.x) * tl);
    acc.y *= expf(-fabsf(dc.y) * tl);
    acc.z *= expf(-fabsf(dc.z) * tl);
    acc.w *= expf(-fabsf(dc.w) * tl);
    *(float4*)(hout + ((size_t)i * TAPS + n) * DD + c0) = acc;
}

// ---------------------------------------------------------------------------
// Fused causal-conv (blocks 0..4095) + depthwise conv (4096..8191). Unchanged.
// ---------------------------------------------------------------------------
#define CTT 64
#define CCC 32
__global__ __launch_bounds__(256) void convdw_kernel(
    const float* __restrict__ v, const float* __restrict__ hflt, float* __restrict__ y,
    const unsigned short* __restrict__ ctrl, int ld,
    const float* __restrict__ cw, const float* __restrict__ cb,
    unsigned short* __restrict__ xc)
{
    const int bid = blockIdx.x;
    const int tid = threadIdx.x;

    if (bid >= 4096) {
        size_t idx = (size_t)(bid - 4096) * 256 + tid;
        int c8 = (int)(idx & 127) * 8;
        size_t bt = idx >> 7;
        int t = (int)(bt & (LL - 1));

        const unsigned short* base = ctrl + bt * ld + c8;
        bf16x8 xm = {}, xp = {};
        bf16x8 x0 = *(const bf16x8*)(base);
        if (t > 0)      xm = *(const bf16x8*)(base - ld);
        if (t < LL - 1) xp = *(const bf16x8*)(base + ld);

        bf16x8 o;
        #pragma unroll
        for (int q = 0; q < 8; ++q) {
            int c = c8 + q;
            float r = cw[0 * DD + c] * bf2f((unsigned short)xm[q])
                    + cw[1 * DD + c] * bf2f((unsigned short)x0[q])
                    + cw[2 * DD + c] * bf2f((unsigned short)xp[q])
                    + cb[c];
            o[q] = (short)f2bf(r);
        }
        *(bf16x8*)(xc + bt * DD + c8) = o;
        return;
    }

    const int t0 = (bid & 63) * CTT;
    const int c0 = ((bid >> 6) & 31) * CCC;
    const int b  = bid >> 11;

    __shared__ float sv[128][CCC];
    __shared__ float sh[TAPS][CCC];

    const float* vb = v + (size_t)b * LL * DD;
    #pragma unroll
    for (int q = 0; q < 4; ++q) {
        int idx = tid + q * 256;
        int row = idx >> 3;
        int c4  = (idx & 7) * 4;
        int t = t0 - 64 + row;
        float4 val = make_float4(0.f, 0.f, 0.f, 0.f);
        if (t >= 0) val = *(const float4*)(vb + (size_t)t * DD + c0 + c4);
        *(float4*)(&sv[row][c4]) = val;
    }
    #pragma unroll
    for (int q = 0; q < 2; ++q) {
        int idx = tid + q * 256;
        int u   = idx >> 3;
        int c4  = (idx & 7) * 4;
        *(float4*)(&sh[u][c4]) = *(const float4*)(hflt + (size_t)u * DD + c0 + c4);
    }
    __syncthreads();

    const int tx = tid & 31;
    const int ty = tid >> 5;
    const int R0 = 64 + ty * 8;

    float acc[8] = {};
    #pragma unroll
    for (int m = 0; m < 8; ++m) {
        float W[15];
        #pragma unroll
        for (int p = 0; p < 15; ++p) W[p] = sv[R0 - 8 * m - 7 + p][tx];
        float h8[8];
        #pragma unroll
        for (int du = 0; du < 8; ++du) h8[du] = sh[8 * m + du][tx];
        #pragma unroll
        for (int du = 0; du < 8; ++du)
            #pragma unroll
            for (int j = 0; j < 8; ++j)
                acc[j] += h8[du] * W[7 + j - du];
    }

    float* yb = y + ((size_t)b * LL + t0) * DD + c0;
    #pragma unroll
    for (int j = 0; j < 8; ++j) yb[(size_t)(ty * 8 + j) * DD + tx] = acc[j];
}

// ---------------------------------------------------------------------------
// m201-style 8-phase 256x256 GEMM for in_proj. 512 thr, 8 waves (2M x 4N),
// per-wave 128x64 (M_REP=8, N_REP=4), BK=64, dbuf 2x64KB.
// Staging ONLY ever targets buf[(t+1)&1] (never the read buffer) -> race-free.
// Halves staged 1/phase in order {A-k0, B-k0, A-k1, B-k1}; vmcnt(4) at ends of
// phases 1 and 3 guarantees each K-sub landed >=2 phases before first ds_read.
// Per phase: {subtile ds_read + 2 gl_lds -> barrier -> lgkmcnt(0) ->
// setprio(1) 16 MFMA setprio(0) -> barrier}. B-frags live across phase pairs.
// EPI4 epilogue: col<1024 -> f32 V, else bf16 ctrl (ldc 2048).
// ---------------------------------------------------------------------------
__global__ __launch_bounds__(512, 1) void gemm256_8p_kernel(
    const unsigned short* __restrict__ A,    // 8192 x 1024
    const unsigned short* __restrict__ BT,   // 3072 x 1024
    const float* __restrict__ bias,          // 3072
    float* __restrict__ Vout,                // 8192 x 1024 f32
    unsigned short* __restrict__ Cout2)      // 8192 x 2048 bf16
{
    __shared__ char lds[131072];
    const int Nblk = 12;

    const int tid  = threadIdx.x;
    const int wave = tid >> 6;
    const int lane = tid & 63;

    const int nwg  = gridDim.x;              // 384, %8==0
    const int orig = blockIdx.x;
    const int wg   = (orig & 7) * (nwg >> 3) + (orig >> 3);
    const int by   = wg / Nblk;
    const int bx   = wg % Nblk;

    const int wm  = (wave >> 2) * 128;       // 2 waves along M
    const int wn  = (wave & 3) * 64;         // 4 waves along N
    const int llo = lane & 15;
    const int lhi = lane >> 4;

    // ---- staging (pre-swizzled slot within each 64B chunk-row) ----
    const int srow = tid >> 2;               // 0..127
    const int ssl  = tid & 3;
    const int ssrc = ssl ^ ((srow >> 1) & 3);
    const unsigned short* Asrc = A  + (size_t)(by * 256 + srow) * 1024 + ssrc * 8;
    const unsigned short* Bsrc = BT + (size_t)(bx * 256 + srow) * 1024 + ssrc * 8;
    char* ldsp = (char*)lds;
    const int wofs = wave * 1024;            // wave-uniform dest base within 8KB chunk

    // ---- ds_read offsets (kk adds 16384; B region at +32768) ----
    const int slot = lhi ^ ((llo >> 1) & 3);
    int offA[8], offB[4];
    #pragma unroll
    for (int mi = 0; mi < 8; ++mi) {
        int row = wm + mi * 16 + llo;        // 0..255
        offA[mi] = (row >> 7) * 8192 + (row & 127) * 64 + slot * 16;
    }
    #pragma unroll
    for (int ni = 0; ni < 4; ++ni) {
        int row = wn + ni * 16 + llo;        // 0..255
        offB[ni] = 32768 + (row >> 7) * 8192 + (row & 127) * 64 + slot * 16;
    }

    f32x4 acc[8][4] = {};

    // stage half h of tile t: h = 0:A-k0, 1:B-k0, 2:A-k1, 3:B-k1 (2 loads each)
    auto stageHalf = [&](int t, int h) {
        const int bo = (t & 1) * 65536;
        const int k0 = t * 64 + (h >> 1) * 32;
        const unsigned short* src = (h & 1) ? Bsrc : Asrc;
        const int ro = bo + (h & 1) * 32768 + ((h >> 1) * 16384);
        gl_lds16(src + k0,                       ldsp + ro + wofs);
        gl_lds16(src + (size_t)128 * 1024 + k0,  ldsp + ro + 8192 + wofs);
    };

    // prologue: tile 0 fully staged; drain once (allowed outside main loop)
    stageHalf(0, 0); stageHalf(0, 1); stageHalf(0, 2); stageHalf(0, 3);
    asm volatile("s_waitcnt vmcnt(0)" ::: "memory");
    __builtin_amdgcn_sched_barrier(0);
    __builtin_amdgcn_s_barrier();
    __builtin_amdgcn_sched_barrier(0);

    for (int t = 0; t < 16; ++t) {
        const int bo = (t & 1) * 65536;
        const bool st = (t < 15);
        bf16x8 aF[4], bA[4];

        // ================ phase 0: kk=0, mi 0..3 ================
        #pragma unroll
        for (int i = 0; i < 4; ++i) aF[i] = *(const bf16x8*)(ldsp + bo + offA[i]);
        #pragma unroll
        for (int i = 0; i < 4; ++i) bA[i] = *(const bf16x8*)(ldsp + bo + offB[i]);
        if (st) stageHalf(t + 1, 0);
        __builtin_amdgcn_s_barrier();
        asm volatile("s_waitcnt lgkmcnt(0)" ::: "memory");
        __builtin_amdgcn_sched_barrier(0);
        __builtin_amdgcn_s_setprio(1);
        #pragma unroll
        for (int mi = 0; mi < 4; ++mi)
            #pragma unroll
            for (int ni = 0; ni < 4; ++ni)
                acc[mi][ni] = __builtin_amdgcn_mfma_f32_16x16x32_bf16(aF[mi], bA[ni], acc[mi][ni], 0, 0, 0);
        __builtin_amdgcn_s_setprio(0);
        __builtin_amdgcn_s_barrier();

        // ================ phase 1: kk=0, mi 4..7 ================
        #pragma unroll
        for (int i = 0; i < 4; ++i) aF[i] = *(const bf16x8*)(ldsp + bo + offA[4 + i]);
        if (st) stageHalf(t + 1, 1);
        __builtin_amdgcn_s_barrier();
        asm volatile("s_waitcnt lgkmcnt(0)" ::: "memory");
        __builtin_amdgcn_sched_barrier(0);
        __builtin_amdgcn_s_setprio(1);
        #pragma unroll
        for (int mi = 0; mi < 4; ++mi)
            #pragma unroll
            for (int ni = 0; ni < 4; ++ni)
                acc[4 + mi][ni] = __builtin_amdgcn_mfma_f32_16x16x32_bf16(aF[mi], bA[ni], acc[4 + mi][ni], 0, 0, 0);
        __builtin_amdgcn_s_setprio(0);
        if (st) asm volatile("s_waitcnt vmcnt(4)" ::: "memory");
        else    asm volatile("s_waitcnt vmcnt(0)" ::: "memory");
        __builtin_amdgcn_sched_barrier(0);
        __builtin_amdgcn_s_barrier();

        // ================ phase 2: kk=1, mi 0..3 ================
        #pragma unroll
        for (int i = 0; i < 4; ++i) aF[i] = *(const bf16x8*)(ldsp + bo + offA[i] + 16384);
        #pragma unroll
        for (int i = 0; i < 4; ++i) bA[i] = *(const bf16x8*)(ldsp + bo + offB[i] + 16384);
        if (st) stageHalf(t + 1, 2);
        __builtin_amdgcn_s_barrier();
        asm volatile("s_waitcnt lgkmcnt(0)" ::: "memory");
        __builtin_amdgcn_sched_barrier(0);
        __builtin_amdgcn_s_setprio(1);
        #pragma unroll
        for (int mi = 0; mi < 4; ++mi)
            #pragma unroll
            for (int ni = 0; ni < 4; ++ni)
                acc[mi][ni] = __builtin_amdgcn_mfma_f32_16x16x32_bf16(aF[mi], bA[ni], acc[mi][ni], 0, 0, 0);
        __builtin_amdgcn_s_setprio(0);
        __builtin_amdgcn_s_barrier();

        // ================ phase 3: kk=1, mi 4..7 ================
        #pragma unroll
        for (int i = 0; i < 4; ++i) aF[i] = *(const bf16x8*)(ldsp + bo + offA[4 + i] + 16384);
        if (st) stageHalf(t + 1, 3);
        __builtin_amdgcn_s_barrier();
        asm volatile("s_waitcnt lgkmcnt(0)" ::: "memory");
        __builtin_amdgcn_sched_barrier(0);
        __builtin_amdgcn_s_setprio(1);
        #pragma unroll
        for (int mi = 0; mi < 4; ++mi)
            #pragma unroll
            for (int ni = 0; ni < 4; ++ni)
                acc[4 + mi][ni] = __builtin_amdgcn_mfma_f32_16x16x32_bf16(aF[mi], bA[ni], acc[4 + mi][ni], 0, 0, 0);
        __builtin_amdgcn_s_setprio(0);
        if (st) asm volatile("s_waitcnt vmcnt(4)" ::: "memory");
        __builtin_amdgcn_sched_barrier(0);
        __builtin_amdgcn_s_barrier();
    }

    // ---- epilogue: C/D layout col=lane&15, row=(lane>>4)*4+reg ----
    #pragma unroll
    for (int ni = 0; ni < 4; ++ni) {
        const int col = bx * 256 + wn + ni * 16 + llo;
        const float bj = bias[col];
        #pragma unroll
        for (int mi = 0; mi < 8; ++mi) {
            #pragma unroll
            for (int r = 0; r < 4; ++r) {
                const int rowg = by * 256 + wm + mi * 16 + lhi * 4 + r;
                float v = acc[mi][ni][r] + bj;
                if (col < 1024) Vout[(size_t)rowg * 1024 + col] = v;
                else Cout2[(size_t)rowg * 2048 + (col - 1024)] = f2bf(v);
            }
        }
    }
}

// ---------------------------------------------------------------------------
// Round-8 gemmw (kept as control for gates/out): BM=128, BN=256, BK=32,
// 256 thr, tri-buffer 72KB, 2 blocks/CU.
// ---------------------------------------------------------------------------
template <int EPI>
__global__ __launch_bounds__(256, 2) void gemmw_kernel(
    const unsigned short* __restrict__ A,
    const unsigned short* __restrict__ BT,
    const float* __restrict__ bias,
    const float* __restrict__ vconv,
    void* __restrict__ Cout,
    int Nblk,
    void* __restrict__ Cout2)
{
    constexpr int BUFB = 24576;
    __shared__ char lds[3 * BUFB];

    const int tid  = threadIdx.x;
    const int wave = tid >> 6;
    const int lane = tid & 63;

    const int nwg  = gridDim.x;
    const int orig = blockIdx.x;
    const int wg   = (orig & 7) * (nwg >> 3) + (orig >> 3);
    const int by   = wg / Nblk;
    const int bx   = wg % Nblk;

    const int wm  = (wave >> 1) * 64;
    const int wn  = (wave & 1) * 128;
    const int llo = lane & 15;
    const int lhi = lane >> 4;

    const int srow = tid >> 2;
    const int ssl  = tid & 3;
    const int ssrc = ssl ^ ((srow >> 1) & 3);
    const unsigned short* Asrc = A  + (size_t)(by * 128 + srow) * 1024 + ssrc * 8;
    const unsigned short* Bsrc = BT + (size_t)(bx * 256 + srow) * 1024 + ssrc * 8;
    char* ldsp = (char*)lds;
    const int wofs = wave * 1024;

    const int slot = lhi ^ ((llo >> 1) & 3);
    int offA[4], offB[8];
    #pragma unroll
    for (int mi = 0; mi < 4; ++mi) {
        int rowA = wm + mi * 16 + llo;
        offA[mi] = rowA * 64 + slot * 16;
    }
    #pragma unroll
    for (int ni = 0; ni < 8; ++ni) {
        int rowB = wn + ni * 16 + llo;
        offB[ni] = 8192 + rowB * 64 + slot * 16;
    }

    f32x4 acc[4][8] = {};

    auto stageh = [&](int t, int buf, int h) {
        const int bo = buf * BUFB;
        const int k0 = t * 32;
        if (h == 0) {
            gl_lds16(Asrc + k0,                           ldsp + bo + 0     + wofs);
            gl_lds16(Asrc + (size_t)64 * 1024 + k0,       ldsp + bo + 4096  + wofs);
            gl_lds16(Bsrc + k0,                           ldsp + bo + 8192  + wofs);
        } else {
            gl_lds16(Bsrc + (size_t)64 * 1024 + k0,       ldsp + bo + 12288 + wofs);
            gl_lds16(Bsrc + (size_t)128 * 1024 + k0,      ldsp + bo + 16384 + wofs);
            gl_lds16(Bsrc + (size_t)192 * 1024 + k0,      ldsp + bo + 20480 + wofs);
        }
    };

    stageh(0, 0, 0); stageh(0, 0, 1);
    stageh(1, 1, 0); stageh(1, 1, 1);
    asm volatile("s_waitcnt vmcnt(6)" ::: "memory");
    __builtin_amdgcn_sched_barrier(0);
    __builtin_amdgcn_s_barrier();
    __builtin_amdgcn_sched_barrier(0);

    int bcur = 0;
    for (int t = 0; t < 32; ++t) {
        const int bo = bcur * BUFB;
        const int nb = (bcur + 2 >= 3) ? bcur - 1 : bcur + 2;

        bf16x8 a0 = *(const bf16x8*)(ldsp + bo + offA[0]);
        bf16x8 a1 = *(const bf16x8*)(ldsp + bo + offA[1]);
        bf16x8 a2 = *(const bf16x8*)(ldsp + bo + offA[2]);
        bf16x8 a3 = *(const bf16x8*)(ldsp + bo + offA[3]);
        bf16x8 b0 = *(const bf16x8*)(ldsp + bo + offB[0]);
        bf16x8 b1 = *(const bf16x8*)(ldsp + bo + offB[1]);
        bf16x8 b2 = *(const bf16x8*)(ldsp + bo + offB[2]);
        bf16x8 b3 = *(const bf16x8*)(ldsp + bo + offB[3]);
        if (t < 30) stageh(t + 2, nb, 0);
        __builtin_amdgcn_s_barrier();
        __builtin_amdgcn_s_setprio(1);
        acc[0][0] = __builtin_amdgcn_mfma_f32_16x16x32_bf16(a0, b0, acc[0][0], 0, 0, 0);
        acc[0][1] = __builtin_amdgcn_mfma_f32_16x16x32_bf16(a0, b1, acc[0][1], 0, 0, 0);
        acc[0][2] = __builtin_amdgcn_mfma_f32_16x16x32_bf16(a0, b2, acc[0][2], 0, 0, 0);
        acc[0][3] = __builtin_amdgcn_mfma_f32_16x16x32_bf16(a0, b3, acc[0][3], 0, 0, 0);
        acc[1][0] = __builtin_amdgcn_mfma_f32_16x16x32_bf16(a1, b0, acc[1][0], 0, 0, 0);
        acc[1][1] = __builtin_amdgcn_mfma_f32_16x16x32_bf16(a1, b1, acc[1][1], 0, 0, 0);
        acc[1][2] = __builtin_amdgcn_mfma_f32_16x16x32_bf16(a1, b2, acc[1][2], 0, 0, 0);
        acc[1][3] = __builtin_amdgcn_mfma_f32_16x16x32_bf16(a1, b3, acc[1][3], 0, 0, 0);
        acc[2][0] = __builtin_amdgcn_mfma_f32_16x16x32_bf16(a2, b0, acc[2][0], 0, 0, 0);
        acc[2][1] = __builtin_amdgcn_mfma_f32_16x16x32_bf16(a2, b1, acc[2][1], 0, 0, 0);
        acc[2][2] = __builtin_amdgcn_mfma_f32_16x16x32_bf16(a2, b2, acc[2][2], 0, 0, 0);
        acc[2][3] = __builtin_amdgcn_mfma_f32_16x16x32_bf16(a2, b3, acc[2][3], 0, 0, 0);
        acc[3][0] = __builtin_amdgcn_mfma_f32_16x16x32_bf16(a3, b0, acc[3][0], 0, 0, 0);
        acc[3][1] = __builtin_amdgcn_mfma_f32_16x16x32_bf16(a3, b1, acc[3][1], 0, 0, 0);
        acc[3][2] = __builtin_amdgcn_mfma_f32_16x16x32_bf16(a3, b2, acc[3][2], 0, 0, 0);
        acc[3][3] = __builtin_amdgcn_mfma_f32_16x16x32_bf16(a3, b3, acc[3][3], 0, 0, 0);
        __builtin_amdgcn_s_setprio(0);

        b0 = *(const bf16x8*)(ldsp + bo + offB[4]);
        b1 = *(const bf16x8*)(ldsp + bo + offB[5]);
        b2 = *(const bf16x8*)(ldsp + bo + offB[6]);
        b3 = *(const bf16x8*)(ldsp + bo + offB[7]);
        if (t < 30) stageh(t + 2, nb, 1);
        __builtin_amdgcn_s_barrier();
        __builtin_amdgcn_s_setprio(1);
        acc[0][4] = __builtin_amdgcn_mfma_f32_16x16x32_bf16(a0, b0, acc[0][4], 0, 0, 0);
        acc[0][5] = __builtin_amdgcn_mfma_f32_16x16x32_bf16(a0, b1, acc[0][5], 0, 0, 0);
        acc[0][6] = __builtin_amdgcn_mfma_f32_16x16x32_bf16(a0, b2, acc[0][6], 0, 0, 0);
        acc[0][7] = __builtin_amdgcn_mfma_f32_16x16x32_bf16(a0, b3, acc[0][7], 0, 0, 0);
        acc[1][4] = __builtin_amdgcn_mfma_f32_16x16x32_bf16(a1, b0, acc[1][4], 0, 0, 0);
        acc[1][5] = __builtin_amdgcn_mfma_f32_16x16x32_bf16(a1, b1, acc[1][5], 0, 0, 0);
        acc[1][6] = __builtin_amdgcn_mfma_f32_16x16x32_bf16(a1, b2, acc[1][6], 0, 0, 0);
        acc[1][7] = __builtin_amdgcn_mfma_f32_16x16x32_bf16(a1, b3, acc[1][7], 0, 0, 0);
        acc[2][4] = __builtin_amdgcn_mfma_f32_16x16x32_bf16(a2, b0, acc[2][4], 0, 0, 0);
        acc[2][5] = __builtin_amdgcn_mfma_f32_16x16x32_bf16(a2, b1, acc[2][5], 0, 0, 0);
        acc[2][6] = __builtin_amdgcn_mfma_f32_16x16x32_bf16(a2, b2, acc[2][6], 0, 0, 0);
        acc[2][7] = __builtin_amdgcn_mfma_f32_16x16x32_bf16(a2, b3, acc[2][7], 0, 0, 0);
        acc[3][4] = __builtin_amdgcn_mfma_f32_16x16x32_bf16(a3, b0, acc[3][4], 0, 0, 0);
        acc[3][5] = __builtin_amdgcn_mfma_f32_16x16x32_bf16(a3, b1, acc[3][5], 0, 0, 0);
        acc[3][6] = __builtin_amdgcn_mfma_f32_16x16x32_bf16(a3, b2, acc[3][6], 0, 0, 0);
        acc[3][7] = __builtin_amdgcn_mfma_f32_16x16x32_bf16(a3, b3, acc[3][7], 0, 0, 0);
        __builtin_amdgcn_s_setprio(0);

        if (t < 30)       asm volatile("s_waitcnt vmcnt(6)" ::: "memory");
        else if (t == 30) asm volatile("s_waitcnt vmcnt(0)" ::: "memory");
        if (t < 31) {
            __builtin_amdgcn_s_barrier();
            __builtin_amdgcn_sched_barrier(0);
        }
        bcur = (bcur + 1 >= 3) ? 0 : bcur + 1;
    }

    #pragma unroll
    for (int ni = 0; ni < 8; ++ni) {
        const int col = bx * 256 + wn + ni * 16 + llo;
        const float bj = bias[col];
        #pragma unroll
        for (int mi = 0; mi < 4; ++mi) {
            #pragma unroll
            for (int r = 0; r < 4; ++r) {
                const int rowg = by * 128 + wm + mi * 16 + lhi * 4 + r;
                float v = acc[mi][ni][r] + bj;
                if (EPI == 0) {
                    ((float*)Cout)[(size_t)rowg * 1024 + col] = v;
                } else {
                    float xc = bf2f(A[(size_t)rowg * 1024 + col]);
                    float vc = vconv[(size_t)rowg * 1024 + col];
                    float o  = vc * xc * (1.0f / (1.0f + expf(-v)));
                    if (EPI == 2) ((float*)Cout)[(size_t)rowg * 1024 + col] = o;
                    else          ((unsigned short*)Cout)[(size_t)rowg * 1024 + col] = f2bf(o);
                }
            }
        }
    }
}

// ---------------------------------------------------------------------------
extern "C" void kernel_launch(void* const* d_in, const int* in_sizes, int n_in,
                              void* d_out, int out_size, void* d_ws, size_t ws_size,
                              hipStream_t stream) {
    const float* x     = (const float*)d_in[0];
    const float* ipw   = (const float*)d_in[1];
    const float* ipb   = (const float*)d_in[2];
    const float* opw   = (const float*)d_in[3];
    const float* opb   = (const float*)d_in[4];
    const float* freqs = (const float*)d_in[5];
    const float* w1    = (const float*)d_in[6];
    const float* b1    = (const float*)d_in[7];
    const float* w2    = (const float*)d_in[8];
    const float* b2    = (const float*)d_in[9];
    const float* w3    = (const float*)d_in[10];
    const float* b3    = (const float*)d_in[11];
    const float* decay = (const float*)d_in[12];
    const float* cw    = (const float*)d_in[13];
    const float* cb    = (const float*)d_in[14];
    const float* gw    = (const float*)d_in[15];
    const float* gb    = (const float*)d_in[16];
    float* out = (float*)d_out;

    // workspace layout
    char* w = (char*)d_ws;
    float* h             = (float*)w;                                // NORD*TAPS*DD f32
    unsigned short* ipwT = (unsigned short*)(w + (size_t)1048576);   // 3072x1024 bf16
    unsigned short* gw0T = ipwT + (size_t)3072 * 1024;               // 1024x1024
    unsigned short* gw1T = gw0T + (size_t)1024 * 1024;
    unsigned short* opwT = gw1T + (size_t)1024 * 1024;
    unsigned short* xb   = opwT + (size_t)1024 * 1024;               // 8192x1024 bf16 (x, later v2)
    float* V             = (float*)(xb + (size_t)8192 * 1024);       // 8192x1024 f32 (v0, v1)
    unsigned short* ctrlB= (unsigned short*)(V + (size_t)8192 * 1024); // 8192x2048 bf16
    unsigned short* xcB  = ctrlB + (size_t)8192 * 2048;              // 8192x1024 bf16
    float* vconv         = out;                                      // d_out as f32 scratch

    dim3 blk(256);
    dim3 blk512(512);

    // prep: cvt + 4 weight transposes + implicit filters (one dispatch)
    prep_kernel<<<10368, blk, 0, stream>>>(x, xb, ipw, ipwT, gw, gw0T, gw1T,
                                           opw, opwT, freqs, w1, b1, w2, b2, w3, b3, decay, h);

    // fused in_proj (8-phase 256^2): cols<1024 -> V (f32), else -> ctrlB (bf16)
    gemm256_8p_kernel<<<384, blk512, 0, stream>>>(xb, ipwT, ipb, V, ctrlB);

    // order 0: conv(V)->vconv  ||  dwconv(ctrl0)->xcB, then gate GEMM
    convdw_kernel<<<8192, blk, 0, stream>>>(V, h, vconv, ctrlB, 2048, cw, cb, xcB);
    gemmw_kernel<2><<<256, blk, 0, stream>>>(xcB, gw0T, gb, vconv, V, 4, nullptr);

    // order 1
    convdw_kernel<<<8192, blk, 0, stream>>>(V, h + (size_t)TAPS * DD, vconv,
                                            ctrlB + 1024, 2048, cw + (size_t)KW * DD, cb + DD, xcB);
    gemmw_kernel<3><<<256, blk, 0, stream>>>(xcB, gw1T, gb + DD, vconv, xb, 4, nullptr);

    // out = v2 @ opw + opb
    gemmw_kernel<0><<<256, blk, 0, stream>>>(xb, opwT, opb, nullptr, out, 4, nullptr);
}

// Round 10
// 223.763 us; speedup vs baseline: 1.1409x; 1.1409x over previous
//
#include <hip/hip_runtime.h>
#include <math.h>

#define BB 2
#define LL 4096
#define DD 1024
#define NORD 2
#define NEMB 3
#define NFO 64
#define KW 3
#define TAPS 64    // window=exp(-0.5*n) -> e^-32 at n=64; exact truncation in f32

typedef __attribute__((ext_vector_type(8))) short bf16x8;
typedef __attribute__((ext_vector_type(4))) float f32x4;

__device__ __forceinline__ void gl_lds16(const void* g, void* s) {
    __builtin_amdgcn_global_load_lds(
        (const __attribute__((address_space(1))) void*)g,
        (__attribute__((address_space(3))) void*)s, 16, 0, 0);
}

__device__ __forceinline__ float bf2f(unsigned short u) {
    union { unsigned int i; float f; } v; v.i = ((unsigned int)u) << 16; return v.f;
}
__device__ __forceinline__ unsigned short f2bf(float f) {
    union { float f; unsigned int i; } v; v.f = f;
    unsigned int r = v.i + 0x7FFF + ((v.i >> 16) & 1);   // round-nearest-even
    return (unsigned short)(r >> 16);
}

__device__ __forceinline__ float gelu_exact(float x) {
    return 0.5f * x * (1.0f + erff(x * 0.70710678118654752440f));
}

// ---------------------------------------------------------------------------
// Fused prep kernel: cvt + 4 transposes + implicit filter (round-6, unchanged)
// ---------------------------------------------------------------------------
__device__ void wtrans_dev(const float* __restrict__ src, unsigned short* __restrict__ dst,
                           int K, int N, int bx, int by, int tid)
{
    __shared__ float t[32][33];
    const int n0 = bx * 32;
    const int k0 = by * 32;
    const int r = tid >> 5;
    const int c = tid & 31;
    #pragma unroll
    for (int p = 0; p < 4; ++p)
        t[r + p * 8][c] = src[(size_t)(k0 + r + p * 8) * N + n0 + c];
    __syncthreads();
    #pragma unroll
    for (int p = 0; p < 4; ++p)
        dst[(size_t)(n0 + r + p * 8) * K + k0 + c] = f2bf(t[c][r + p * 8]);
}

__global__ __launch_bounds__(256) void prep_kernel(
    const float* __restrict__ x, unsigned short* __restrict__ xb,
    const float* __restrict__ ipw, unsigned short* __restrict__ ipwT,
    const float* __restrict__ gw, unsigned short* __restrict__ gw0T, unsigned short* __restrict__ gw1T,
    const float* __restrict__ opw, unsigned short* __restrict__ opwT,
    const float* __restrict__ freqs, const float* __restrict__ w1, const float* __restrict__ b1,
    const float* __restrict__ w2, const float* __restrict__ b2,
    const float* __restrict__ w3, const float* __restrict__ b3,
    const float* __restrict__ decay, float* __restrict__ hout)
{
    const int bid = blockIdx.x;
    const int tid = threadIdx.x;

    if (bid < 4096) {
        size_t i = ((size_t)bid * 256 + tid) * 8;
        float4 a = *(const float4*)(x + i);
        float4 b = *(const float4*)(x + i + 4);
        bf16x8 o;
        o[0] = (short)f2bf(a.x); o[1] = (short)f2bf(a.y); o[2] = (short)f2bf(a.z); o[3] = (short)f2bf(a.w);
        o[4] = (short)f2bf(b.x); o[5] = (short)f2bf(b.y); o[6] = (short)f2bf(b.z); o[7] = (short)f2bf(b.w);
        *(bf16x8*)(xb + i) = o;
        return;
    }
    if (bid < 7168) { int q = bid - 4096; wtrans_dev(ipw, ipwT, 1024, 3072, q % 96, q / 96, tid); return; }
    if (bid < 8192) { int q = bid - 7168; wtrans_dev(gw, gw0T, 1024, 1024, q % 32, q / 32, tid); return; }
    if (bid < 9216) { int q = bid - 8192; wtrans_dev(gw + (size_t)1024 * 1024, gw1T, 1024, 1024, q % 32, q / 32, tid); return; }
    if (bid < 10240) { int q = bid - 9216; wtrans_dev(opw, opwT, 1024, 1024, q % 32, q / 32, tid); return; }

    const int q = bid - 10240;
    const int i = q / TAPS;
    const int n = q % TAPS;
    const float t = (float)n / (float)(LL - 1);

    __shared__ float s1[NFO];
    __shared__ float s2[NFO];

    if (tid < NFO) {
        float enc[7];
        const float* fr = freqs + i * NEMB;
        const float c2pi = 6.28318530717958647692f;
        #pragma unroll
        for (int e = 0; e < 3; ++e) {
            float a = c2pi * fr[e] * t;
            enc[e]     = sinf(a);
            enc[e + 3] = cosf(a);
        }
        enc[6] = t;
        const float* w = w1 + i * 7 * NFO;
        float acc = b1[i * NFO + tid];
        #pragma unroll
        for (int e = 0; e < 7; ++e) acc += enc[e] * w[e * NFO + tid];
        s1[tid] = gelu_exact(acc);
    }
    __syncthreads();
    if (tid < NFO) {
        const float* w = w2 + i * NFO * NFO;
        float acc = b2[i * NFO + tid];
        #pragma unroll 8
        for (int g = 0; g < NFO; ++g) acc += s1[g] * w[g * NFO + tid];
        s2[tid] = gelu_exact(acc);
    }
    __syncthreads();

    const int c0 = tid * 4;
    const float* w = w3 + (size_t)i * NFO * DD + c0;
    float4 acc = *(const float4*)(b3 + (size_t)i * DD + c0);
    #pragma unroll 8
    for (int g = 0; g < NFO; ++g) {
        float hg = s2[g];
        float4 wv = *(const float4*)(w + (size_t)g * DD);
        acc.x += hg * wv.x; acc.y += hg * wv.y; acc.z += hg * wv.z; acc.w += hg * wv.w;
    }
    float4 dc = *(const float4*)(decay + (size_t)i * DD + c0);
    float tl = t * (float)LL;
    acc.x *= expf(-fabsf(dc.x) * tl);
    acc.y *= expf(-fabsf(dc.y) * tl);
    acc.z *= expf(-fabsf(dc.z) * tl);
    acc.w *= expf(-fabsf(dc.w) * tl);
    *(float4*)(hout + ((size_t)i * TAPS + n) * DD + c0) = acc;
}

// ---------------------------------------------------------------------------
// Fused causal-conv (blocks 0..4095) + depthwise conv (4096..8191). Round-6.
// ---------------------------------------------------------------------------
#define CTT 64
#define CCC 32
__global__ __launch_bounds__(256) void convdw_kernel(
    const float* __restrict__ v, const float* __restrict__ hflt, float* __restrict__ y,
    const unsigned short* __restrict__ ctrl, int ld,
    const float* __restrict__ cw, const float* __restrict__ cb,
    unsigned short* __restrict__ xc)
{
    const int bid = blockIdx.x;
    const int tid = threadIdx.x;

    if (bid >= 4096) {
        size_t idx = (size_t)(bid - 4096) * 256 + tid;
        int c8 = (int)(idx & 127) * 8;
        size_t bt = idx >> 7;
        int t = (int)(bt & (LL - 1));

        const unsigned short* base = ctrl + bt * ld + c8;
        bf16x8 xm = {}, xp = {};
        bf16x8 x0 = *(const bf16x8*)(base);
        if (t > 0)      xm = *(const bf16x8*)(base - ld);
        if (t < LL - 1) xp = *(const bf16x8*)(base + ld);

        bf16x8 o;
        #pragma unroll
        for (int q = 0; q < 8; ++q) {
            int c = c8 + q;
            float r = cw[0 * DD + c] * bf2f((unsigned short)xm[q])
                    + cw[1 * DD + c] * bf2f((unsigned short)x0[q])
                    + cw[2 * DD + c] * bf2f((unsigned short)xp[q])
                    + cb[c];
            o[q] = (short)f2bf(r);
        }
        *(bf16x8*)(xc + bt * DD + c8) = o;
        return;
    }

    const int t0 = (bid & 63) * CTT;
    const int c0 = ((bid >> 6) & 31) * CCC;
    const int b  = bid >> 11;

    __shared__ float sv[128][CCC];
    __shared__ float sh[TAPS][CCC];

    const float* vb = v + (size_t)b * LL * DD;
    #pragma unroll
    for (int q = 0; q < 4; ++q) {
        int idx = tid + q * 256;
        int row = idx >> 3;
        int c4  = (idx & 7) * 4;
        int t = t0 - 64 + row;
        float4 val = make_float4(0.f, 0.f, 0.f, 0.f);
        if (t >= 0) val = *(const float4*)(vb + (size_t)t * DD + c0 + c4);
        *(float4*)(&sv[row][c4]) = val;
    }
    #pragma unroll
    for (int q = 0; q < 2; ++q) {
        int idx = tid + q * 256;
        int u   = idx >> 3;
        int c4  = (idx & 7) * 4;
        *(float4*)(&sh[u][c4]) = *(const float4*)(hflt + (size_t)u * DD + c0 + c4);
    }
    __syncthreads();

    const int tx = tid & 31;
    const int ty = tid >> 5;
    const int R0 = 64 + ty * 8;

    float acc[8] = {};
    #pragma unroll
    for (int m = 0; m < 8; ++m) {
        float W[15];
        #pragma unroll
        for (int p = 0; p < 15; ++p) W[p] = sv[R0 - 8 * m - 7 + p][tx];
        float h8[8];
        #pragma unroll
        for (int du = 0; du < 8; ++du) h8[du] = sh[8 * m + du][tx];
        #pragma unroll
        for (int du = 0; du < 8; ++du)
            #pragma unroll
            for (int j = 0; j < 8; ++j)
                acc[j] += h8[du] * W[7 + j - du];
    }

    float* yb = y + ((size_t)b * LL + t0) * DD + c0;
    #pragma unroll
    for (int j = 0; j < 8; ++j) yb[(size_t)(ty * 8 + j) * DD + tx] = acc[j];
}

// ---------------------------------------------------------------------------
// Round-6 tri-buffer GEMM (best measured: 228 us total) with ONE change:
// epilogue loop order mi{r{ni}} so each row's four 64B segments are issued
// back-to-back (full 128B/256B L2 lines -> no half-dirty-line writeback,
// which round-6/8 counters showed as 1.5-2.2x WRITE amplification).
// EPI 0: f32  2: f32 gate-epi  3: bf16 gate-epi  4: split V f32/ctrl bf16
// ---------------------------------------------------------------------------
template <int EPI>
__global__ __launch_bounds__(512, 1) void gemm8p_kernel(
    const unsigned short* __restrict__ A,    // M x 1024
    const unsigned short* __restrict__ BT,   // N x 1024
    const float* __restrict__ bias,          // N
    const float* __restrict__ vconv,         // M x 1024 f32 (EPI 2/3)
    void* __restrict__ Cout,
    int Nblk,
    void* __restrict__ Cout2)
{
    constexpr int BUFB = 49152;              // A 32KB (4 chunks) + B 16KB (2 chunks)
    __shared__ char lds[3 * BUFB];

    const int tid  = threadIdx.x;
    const int wave = tid >> 6;
    const int lane = tid & 63;

    // bijective XCD swizzle (grid % 8 == 0: 768 or 256)
    const int nwg  = gridDim.x;
    const int orig = blockIdx.x;
    const int wg   = (orig & 7) * (nwg >> 3) + (orig >> 3);
    const int by   = wg / Nblk;
    const int bx   = wg % Nblk;

    const int wm  = (wave >> 1) * 64;        // 4 waves along M
    const int wn  = (wave & 1) * 64;         // 2 waves along N
    const int llo = lane & 15;
    const int lhi = lane >> 4;

    // ---- staging (pre-swizzled slot within each 64B chunk-row) ----
    const int srow = tid >> 2;               // 0..127 (chunk row)
    const int csl  = tid & 3;
    const int csrc = csl ^ ((srow >> 1) & 3);
    const unsigned short* Asrc = A  + (size_t)(by * 256 + srow) * 1024 + csrc * 8;
    const unsigned short* Bsrc = BT + (size_t)(bx * 128 + srow) * 1024 + csrc * 8;
    char* ldsp = (char*)lds;
    const int wofs = wave * 1024;            // wave-uniform dest base within chunk

    // ---- ds_read offsets (kk=0; kk=1 adds 8192) ----
    const int slot = lhi ^ ((llo >> 1) & 3);
    int offA[4], offB[4];
    #pragma unroll
    for (int mi = 0; mi < 4; ++mi) {
        int rowA = wm + mi * 16 + llo;       // 0..255
        offA[mi] = (rowA >> 7) * 16384 + (rowA & 127) * 64 + slot * 16;
    }
    #pragma unroll
    for (int ni = 0; ni < 4; ++ni) {
        int rowB = wn + ni * 16 + llo;       // 0..127
        offB[ni] = 32768 + rowB * 64 + slot * 16;
    }

    f32x4 acc[4][4] = {};

    // prologue: tile 0 -> buf0, tile 1 -> buf1 (12 loads); wait for tile 0
    {
        gl_lds16(Asrc,                        ldsp + 0 + wofs);
        gl_lds16(Asrc + 32,                   ldsp + 8192 + wofs);
        gl_lds16(Asrc + (size_t)128 * 1024,       ldsp + 16384 + wofs);
        gl_lds16(Asrc + (size_t)128 * 1024 + 32,  ldsp + 24576 + wofs);
        gl_lds16(Bsrc,                        ldsp + 32768 + wofs);
        gl_lds16(Bsrc + 32,                   ldsp + 40960 + wofs);
        gl_lds16(Asrc + 64,                   ldsp + BUFB + 0 + wofs);
        gl_lds16(Asrc + 96,                   ldsp + BUFB + 8192 + wofs);
        gl_lds16(Asrc + (size_t)128 * 1024 + 64,  ldsp + BUFB + 16384 + wofs);
        gl_lds16(Asrc + (size_t)128 * 1024 + 96,  ldsp + BUFB + 24576 + wofs);
        gl_lds16(Bsrc + 64,                   ldsp + BUFB + 32768 + wofs);
        gl_lds16(Bsrc + 96,                   ldsp + BUFB + 40960 + wofs);
    }
    asm volatile("s_waitcnt vmcnt(6)" ::: "memory");
    __builtin_amdgcn_sched_barrier(0);
    __builtin_amdgcn_s_barrier();
    __builtin_amdgcn_sched_barrier(0);

    int bcur = 0;
    for (int t = 0; t < 16; ++t) {
        const int bo  = bcur * BUFB;
        const int nb  = (bcur + 2 >= 3) ? bcur - 1 : bcur + 2;
        const int bo2 = nb * BUFB;
        const int k2  = (t + 2) * 64;
        const bool st = (t < 14);

        // ---- phase 0: kk = 0 ----
        bf16x8 a0 = *(const bf16x8*)(ldsp + bo + offA[0]);
        bf16x8 a1 = *(const bf16x8*)(ldsp + bo + offA[1]);
        bf16x8 a2 = *(const bf16x8*)(ldsp + bo + offA[2]);
        bf16x8 a3 = *(const bf16x8*)(ldsp + bo + offA[3]);
        bf16x8 b0 = *(const bf16x8*)(ldsp + bo + offB[0]);
        bf16x8 b1 = *(const bf16x8*)(ldsp + bo + offB[1]);
        bf16x8 b2 = *(const bf16x8*)(ldsp + bo + offB[2]);
        bf16x8 b3 = *(const bf16x8*)(ldsp + bo + offB[3]);
        if (st) {   // stage t+2: A rows 0-127
            gl_lds16(Asrc + k2,      ldsp + bo2 + 0 + wofs);
            gl_lds16(Asrc + 32 + k2, ldsp + bo2 + 8192 + wofs);
        }
        __builtin_amdgcn_s_barrier();
        __builtin_amdgcn_s_setprio(1);
        acc[0][0] = __builtin_amdgcn_mfma_f32_16x16x32_bf16(a0, b0, acc[0][0], 0, 0, 0);
        acc[0][1] = __builtin_amdgcn_mfma_f32_16x16x32_bf16(a0, b1, acc[0][1], 0, 0, 0);
        acc[0][2] = __builtin_amdgcn_mfma_f32_16x16x32_bf16(a0, b2, acc[0][2], 0, 0, 0);
        acc[0][3] = __builtin_amdgcn_mfma_f32_16x16x32_bf16(a0, b3, acc[0][3], 0, 0, 0);
        acc[1][0] = __builtin_amdgcn_mfma_f32_16x16x32_bf16(a1, b0, acc[1][0], 0, 0, 0);
        acc[1][1] = __builtin_amdgcn_mfma_f32_16x16x32_bf16(a1, b1, acc[1][1], 0, 0, 0);
        acc[1][2] = __builtin_amdgcn_mfma_f32_16x16x32_bf16(a1, b2, acc[1][2], 0, 0, 0);
        acc[1][3] = __builtin_amdgcn_mfma_f32_16x16x32_bf16(a1, b3, acc[1][3], 0, 0, 0);
        acc[2][0] = __builtin_amdgcn_mfma_f32_16x16x32_bf16(a2, b0, acc[2][0], 0, 0, 0);
        acc[2][1] = __builtin_amdgcn_mfma_f32_16x16x32_bf16(a2, b1, acc[2][1], 0, 0, 0);
        acc[2][2] = __builtin_amdgcn_mfma_f32_16x16x32_bf16(a2, b2, acc[2][2], 0, 0, 0);
        acc[2][3] = __builtin_amdgcn_mfma_f32_16x16x32_bf16(a2, b3, acc[2][3], 0, 0, 0);
        acc[3][0] = __builtin_amdgcn_mfma_f32_16x16x32_bf16(a3, b0, acc[3][0], 0, 0, 0);
        acc[3][1] = __builtin_amdgcn_mfma_f32_16x16x32_bf16(a3, b1, acc[3][1], 0, 0, 0);
        acc[3][2] = __builtin_amdgcn_mfma_f32_16x16x32_bf16(a3, b2, acc[3][2], 0, 0, 0);
        acc[3][3] = __builtin_amdgcn_mfma_f32_16x16x32_bf16(a3, b3, acc[3][3], 0, 0, 0);
        __builtin_amdgcn_s_setprio(0);

        // ---- phase 1: kk = 1 ----
        a0 = *(const bf16x8*)(ldsp + bo + offA[0] + 8192);
        a1 = *(const bf16x8*)(ldsp + bo + offA[1] + 8192);
        a2 = *(const bf16x8*)(ldsp + bo + offA[2] + 8192);
        a3 = *(const bf16x8*)(ldsp + bo + offA[3] + 8192);
        b0 = *(const bf16x8*)(ldsp + bo + offB[0] + 8192);
        b1 = *(const bf16x8*)(ldsp + bo + offB[1] + 8192);
        b2 = *(const bf16x8*)(ldsp + bo + offB[2] + 8192);
        b3 = *(const bf16x8*)(ldsp + bo + offB[3] + 8192);
        if (st) {   // stage t+2: A rows 128-255 + B
            gl_lds16(Asrc + (size_t)128 * 1024 + k2,      ldsp + bo2 + 16384 + wofs);
            gl_lds16(Asrc + (size_t)128 * 1024 + 32 + k2, ldsp + bo2 + 24576 + wofs);
            gl_lds16(Bsrc + k2,      ldsp + bo2 + 32768 + wofs);
            gl_lds16(Bsrc + 32 + k2, ldsp + bo2 + 40960 + wofs);
        }
        __builtin_amdgcn_s_barrier();
        __builtin_amdgcn_s_setprio(1);
        acc[0][0] = __builtin_amdgcn_mfma_f32_16x16x32_bf16(a0, b0, acc[0][0], 0, 0, 0);
        acc[0][1] = __builtin_amdgcn_mfma_f32_16x16x32_bf16(a0, b1, acc[0][1], 0, 0, 0);
        acc[0][2] = __builtin_amdgcn_mfma_f32_16x16x32_bf16(a0, b2, acc[0][2], 0, 0, 0);
        acc[0][3] = __builtin_amdgcn_mfma_f32_16x16x32_bf16(a0, b3, acc[0][3], 0, 0, 0);
        acc[1][0] = __builtin_amdgcn_mfma_f32_16x16x32_bf16(a1, b0, acc[1][0], 0, 0, 0);
        acc[1][1] = __builtin_amdgcn_mfma_f32_16x16x32_bf16(a1, b1, acc[1][1], 0, 0, 0);
        acc[1][2] = __builtin_amdgcn_mfma_f32_16x16x32_bf16(a1, b2, acc[1][2], 0, 0, 0);
        acc[1][3] = __builtin_amdgcn_mfma_f32_16x16x32_bf16(a1, b3, acc[1][3], 0, 0, 0);
        acc[2][0] = __builtin_amdgcn_mfma_f32_16x16x32_bf16(a2, b0, acc[2][0], 0, 0, 0);
        acc[2][1] = __builtin_amdgcn_mfma_f32_16x16x32_bf16(a2, b1, acc[2][1], 0, 0, 0);
        acc[2][2] = __builtin_amdgcn_mfma_f32_16x16x32_bf16(a2, b2, acc[2][2], 0, 0, 0);
        acc[2][3] = __builtin_amdgcn_mfma_f32_16x16x32_bf16(a2, b3, acc[2][3], 0, 0, 0);
        acc[3][0] = __builtin_amdgcn_mfma_f32_16x16x32_bf16(a3, b0, acc[3][0], 0, 0, 0);
        acc[3][1] = __builtin_amdgcn_mfma_f32_16x16x32_bf16(a3, b1, acc[3][1], 0, 0, 0);
        acc[3][2] = __builtin_amdgcn_mfma_f32_16x16x32_bf16(a3, b2, acc[3][2], 0, 0, 0);
        acc[3][3] = __builtin_amdgcn_mfma_f32_16x16x32_bf16(a3, b3, acc[3][3], 0, 0, 0);
        __builtin_amdgcn_s_setprio(0);

        // ---- tile end: tile t+1 landed; t+2 stays in flight ----
        if (st)           asm volatile("s_waitcnt vmcnt(6)" ::: "memory");
        else if (t == 14) asm volatile("s_waitcnt vmcnt(0)" ::: "memory");
        if (t < 15) {
            __builtin_amdgcn_s_barrier();
            __builtin_amdgcn_sched_barrier(0);
        }
        bcur = (bcur + 1 >= 3) ? 0 : bcur + 1;
    }

    // ---- epilogue, row-contiguous order: mi { r { ni } } ----
    float bj[4];
    #pragma unroll
    for (int ni = 0; ni < 4; ++ni) bj[ni] = bias[bx * 128 + wn + ni * 16 + llo];
    #pragma unroll
    for (int mi = 0; mi < 4; ++mi) {
        #pragma unroll
        for (int r = 0; r < 4; ++r) {
            const int rowg = by * 256 + wm + mi * 16 + lhi * 4 + r;
            #pragma unroll
            for (int ni = 0; ni < 4; ++ni) {
                const int col = bx * 128 + wn + ni * 16 + llo;
                float v = acc[mi][ni][r] + bj[ni];
                if (EPI == 0) {
                    ((float*)Cout)[(size_t)rowg * 1024 + col] = v;
                } else if (EPI == 4) {
                    if (col < 1024) ((float*)Cout)[(size_t)rowg * 1024 + col] = v;
                    else ((unsigned short*)Cout2)[(size_t)rowg * 2048 + (col - 1024)] = f2bf(v);
                } else {
                    float xc = bf2f(A[(size_t)rowg * 1024 + col]);
                    float vc = vconv[(size_t)rowg * 1024 + col];
                    float o  = vc * xc * (1.0f / (1.0f + expf(-v)));
                    if (EPI == 2) ((float*)Cout)[(size_t)rowg * 1024 + col] = o;
                    else          ((unsigned short*)Cout)[(size_t)rowg * 1024 + col] = f2bf(o);
                }
            }
        }
    }
}

// ---------------------------------------------------------------------------
extern "C" void kernel_launch(void* const* d_in, const int* in_sizes, int n_in,
                              void* d_out, int out_size, void* d_ws, size_t ws_size,
                              hipStream_t stream) {
    const float* x     = (const float*)d_in[0];
    const float* ipw   = (const float*)d_in[1];
    const float* ipb   = (const float*)d_in[2];
    const float* opw   = (const float*)d_in[3];
    const float* opb   = (const float*)d_in[4];
    const float* freqs = (const float*)d_in[5];
    const float* w1    = (const float*)d_in[6];
    const float* b1    = (const float*)d_in[7];
    const float* w2    = (const float*)d_in[8];
    const float* b2    = (const float*)d_in[9];
    const float* w3    = (const float*)d_in[10];
    const float* b3    = (const float*)d_in[11];
    const float* decay = (const float*)d_in[12];
    const float* cw    = (const float*)d_in[13];
    const float* cb    = (const float*)d_in[14];
    const float* gw    = (const float*)d_in[15];
    const float* gb    = (const float*)d_in[16];
    float* out = (float*)d_out;

    // workspace layout
    char* w = (char*)d_ws;
    float* h             = (float*)w;                                // NORD*TAPS*DD f32
    unsigned short* ipwT = (unsigned short*)(w + (size_t)1048576);   // 3072x1024 bf16
    unsigned short* gw0T = ipwT + (size_t)3072 * 1024;               // 1024x1024
    unsigned short* gw1T = gw0T + (size_t)1024 * 1024;
    unsigned short* opwT = gw1T + (size_t)1024 * 1024;
    unsigned short* xb   = opwT + (size_t)1024 * 1024;               // 8192x1024 bf16 (x, later v2)
    float* V             = (float*)(xb + (size_t)8192 * 1024);       // 8192x1024 f32 (v0, v1)
    unsigned short* ctrlB= (unsigned short*)(V + (size_t)8192 * 1024); // 8192x2048 bf16
    unsigned short* xcB  = ctrlB + (size_t)8192 * 2048;              // 8192x1024 bf16
    float* vconv         = out;                                      // d_out as f32 scratch

    dim3 blk(256);
    dim3 blk512(512);

    // prep: cvt + 4 weight transposes + implicit filters (one dispatch)
    prep_kernel<<<10368, blk, 0, stream>>>(x, xb, ipw, ipwT, gw, gw0T, gw1T,
                                           opw, opwT, freqs, w1, b1, w2, b2, w3, b3, decay, h);

    // fused in_proj: cols<1024 -> V (f32), cols>=1024 -> ctrlB (bf16)
    gemm8p_kernel<4><<<768, blk512, 0, stream>>>(xb, ipwT, ipb, nullptr, V, 24, ctrlB);

    // order 0: conv(V)->vconv  ||  dwconv(ctrl0)->xcB, then gate GEMM
    convdw_kernel<<<8192, blk, 0, stream>>>(V, h, vconv, ctrlB, 2048, cw, cb, xcB);
    gemm8p_kernel<2><<<256, blk512, 0, stream>>>(xcB, gw0T, gb, vconv, V, 8, nullptr);

    // order 1
    convdw_kernel<<<8192, blk, 0, stream>>>(V, h + (size_t)TAPS * DD, vconv,
                                            ctrlB + 1024, 2048, cw + (size_t)KW * DD, cb + DD, xcB);
    gemm8p_kernel<3><<<256, blk512, 0, stream>>>(xcB, gw1T, gb + DD, vconv, xb, 8, nullptr);

    // out = v2 @ opw + opb
    gemm8p_kernel<0><<<256, blk512, 0, stream>>>(xb, opwT, opb, nullptr, out, 8, nullptr);
}

// Round 11
// 212.920 us; speedup vs baseline: 1.1990x; 1.0509x over previous
//
#include <hip/hip_runtime.h>
#include <math.h>

#define BB 2
#define LL 4096
#define DD 1024
#define NORD 2
#define NEMB 3
#define NFO 64
#define KW 3
#define TAPS 64    // window=exp(-0.5*n) -> e^-32 at n=64; exact truncation in f32

typedef __attribute__((ext_vector_type(8))) short bf16x8;
typedef __attribute__((ext_vector_type(4))) float f32x4;

__device__ __forceinline__ void gl_lds16(const void* g, void* s) {
    __builtin_amdgcn_global_load_lds(
        (const __attribute__((address_space(1))) void*)g,
        (__attribute__((address_space(3))) void*)s, 16, 0, 0);
}

__device__ __forceinline__ float bf2f(unsigned short u) {
    union { unsigned int i; float f; } v; v.i = ((unsigned int)u) << 16; return v.f;
}
__device__ __forceinline__ unsigned short f2bf(float f) {
    union { float f; unsigned int i; } v; v.f = f;
    unsigned int r = v.i + 0x7FFF + ((v.i >> 16) & 1);   // round-nearest-even
    return (unsigned short)(r >> 16);
}

__device__ __forceinline__ float gelu_exact(float x) {
    return 0.5f * x * (1.0f + erff(x * 0.70710678118654752440f));
}

// ---------------------------------------------------------------------------
// Fused prep kernel: cvt + 4 transposes + implicit filter (unchanged)
// ---------------------------------------------------------------------------
__device__ void wtrans_dev(const float* __restrict__ src, unsigned short* __restrict__ dst,
                           int K, int N, int bx, int by, int tid)
{
    __shared__ float t[32][33];
    const int n0 = bx * 32;
    const int k0 = by * 32;
    const int r = tid >> 5;
    const int c = tid & 31;
    #pragma unroll
    for (int p = 0; p < 4; ++p)
        t[r + p * 8][c] = src[(size_t)(k0 + r + p * 8) * N + n0 + c];
    __syncthreads();
    #pragma unroll
    for (int p = 0; p < 4; ++p)
        dst[(size_t)(n0 + r + p * 8) * K + k0 + c] = f2bf(t[c][r + p * 8]);
}

__global__ __launch_bounds__(256) void prep_kernel(
    const float* __restrict__ x, unsigned short* __restrict__ xb,
    const float* __restrict__ ipw, unsigned short* __restrict__ ipwT,
    const float* __restrict__ gw, unsigned short* __restrict__ gw0T, unsigned short* __restrict__ gw1T,
    const float* __restrict__ opw, unsigned short* __restrict__ opwT,
    const float* __restrict__ freqs, const float* __restrict__ w1, const float* __restrict__ b1,
    const float* __restrict__ w2, const float* __restrict__ b2,
    const float* __restrict__ w3, const float* __restrict__ b3,
    const float* __restrict__ decay, float* __restrict__ hout)
{
    const int bid = blockIdx.x;
    const int tid = threadIdx.x;

    if (bid < 4096) {
        size_t i = ((size_t)bid * 256 + tid) * 8;
        float4 a = *(const float4*)(x + i);
        float4 b = *(const float4*)(x + i + 4);
        bf16x8 o;
        o[0] = (short)f2bf(a.x); o[1] = (short)f2bf(a.y); o[2] = (short)f2bf(a.z); o[3] = (short)f2bf(a.w);
        o[4] = (short)f2bf(b.x); o[5] = (short)f2bf(b.y); o[6] = (short)f2bf(b.z); o[7] = (short)f2bf(b.w);
        *(bf16x8*)(xb + i) = o;
        return;
    }
    if (bid < 7168) { int q = bid - 4096; wtrans_dev(ipw, ipwT, 1024, 3072, q % 96, q / 96, tid); return; }
    if (bid < 8192) { int q = bid - 7168; wtrans_dev(gw, gw0T, 1024, 1024, q % 32, q / 32, tid); return; }
    if (bid < 9216) { int q = bid - 8192; wtrans_dev(gw + (size_t)1024 * 1024, gw1T, 1024, 1024, q % 32, q / 32, tid); return; }
    if (bid < 10240) { int q = bid - 9216; wtrans_dev(opw, opwT, 1024, 1024, q % 32, q / 32, tid); return; }

    const int q = bid - 10240;
    const int i = q / TAPS;
    const int n = q % TAPS;
    const float t = (float)n / (float)(LL - 1);

    __shared__ float s1[NFO];
    __shared__ float s2[NFO];

    if (tid < NFO) {
        float enc[7];
        const float* fr = freqs + i * NEMB;
        const float c2pi = 6.28318530717958647692f;
        #pragma unroll
        for (int e = 0; e < 3; ++e) {
            float a = c2pi * fr[e] * t;
            enc[e]     = sinf(a);
            enc[e + 3] = cosf(a);
        }
        enc[6] = t;
        const float* w = w1 + i * 7 * NFO;
        float acc = b1[i * NFO + tid];
        #pragma unroll
        for (int e = 0; e < 7; ++e) acc += enc[e] * w[e * NFO + tid];
        s1[tid] = gelu_exact(acc);
    }
    __syncthreads();
    if (tid < NFO) {
        const float* w = w2 + i * NFO * NFO;
        float acc = b2[i * NFO + tid];
        #pragma unroll 8
        for (int g = 0; g < NFO; ++g) acc += s1[g] * w[g * NFO + tid];
        s2[tid] = gelu_exact(acc);
    }
    __syncthreads();

    const int c0 = tid * 4;
    const float* w = w3 + (size_t)i * NFO * DD + c0;
    float4 acc = *(const float4*)(b3 + (size_t)i * DD + c0);
    #pragma unroll 8
    for (int g = 0; g < NFO; ++g) {
        float hg = s2[g];
        float4 wv = *(const float4*)(w + (size_t)g * DD);
        acc.x += hg * wv.x; acc.y += hg * wv.y; acc.z += hg * wv.z; acc.w += hg * wv.w;
    }
    float4 dc = *(const float4*)(decay + (size_t)i * DD + c0);
    float tl = t * (float)LL;
    acc.x *= expf(-fabsf(dc.x) * tl);
    acc.y *= expf(-fabsf(dc.y) * tl);
    acc.z *= expf(-fabsf(dc.z) * tl);
    acc.w *= expf(-fabsf(dc.w) * tl);
    *(float4*)(hout + ((size_t)i * TAPS + n) * DD + c0) = acc;
}

// ---------------------------------------------------------------------------
// Fused causal-conv (blocks 0..4095, bf16 in -> bf16 out, f32 accum)
//       + depthwise conv (4096..8191, bf16 -> bf16)
// ---------------------------------------------------------------------------
#define CTT 64
#define CCC 32
__global__ __launch_bounds__(256) void convdw_kernel(
    const unsigned short* __restrict__ v, const float* __restrict__ hflt,
    unsigned short* __restrict__ y,
    const unsigned short* __restrict__ ctrl, int ld,
    const float* __restrict__ cw, const float* __restrict__ cb,
    unsigned short* __restrict__ xc)
{
    const int bid = blockIdx.x;
    const int tid = threadIdx.x;

    if (bid >= 4096) {
        size_t idx = (size_t)(bid - 4096) * 256 + tid;
        int c8 = (int)(idx & 127) * 8;
        size_t bt = idx >> 7;
        int t = (int)(bt & (LL - 1));

        const unsigned short* base = ctrl + bt * ld + c8;
        bf16x8 xm = {}, xp = {};
        bf16x8 x0 = *(const bf16x8*)(base);
        if (t > 0)      xm = *(const bf16x8*)(base - ld);
        if (t < LL - 1) xp = *(const bf16x8*)(base + ld);

        bf16x8 o;
        #pragma unroll
        for (int q = 0; q < 8; ++q) {
            int c = c8 + q;
            float r = cw[0 * DD + c] * bf2f((unsigned short)xm[q])
                    + cw[1 * DD + c] * bf2f((unsigned short)x0[q])
                    + cw[2 * DD + c] * bf2f((unsigned short)xp[q])
                    + cb[c];
            o[q] = (short)f2bf(r);
        }
        *(bf16x8*)(xc + bt * DD + c8) = o;
        return;
    }

    const int t0 = (bid & 63) * CTT;
    const int c0 = ((bid >> 6) & 31) * CCC;
    const int b  = bid >> 11;

    __shared__ float sv[128][CCC];
    __shared__ float sh[TAPS][CCC];

    const unsigned short* vb = v + (size_t)b * LL * DD;
    #pragma unroll
    for (int q = 0; q < 2; ++q) {
        int idx = tid + q * 256;          // 512 units of 8 channels: 128 rows x 4
        int row = idx >> 2;
        int c8  = (idx & 3) * 8;
        int t = t0 - 64 + row;
        float4 lo = make_float4(0.f, 0.f, 0.f, 0.f);
        float4 hi = make_float4(0.f, 0.f, 0.f, 0.f);
        if (t >= 0) {
            bf16x8 val = *(const bf16x8*)(vb + (size_t)t * DD + c0 + c8);
            lo.x = bf2f((unsigned short)val[0]); lo.y = bf2f((unsigned short)val[1]);
            lo.z = bf2f((unsigned short)val[2]); lo.w = bf2f((unsigned short)val[3]);
            hi.x = bf2f((unsigned short)val[4]); hi.y = bf2f((unsigned short)val[5]);
            hi.z = bf2f((unsigned short)val[6]); hi.w = bf2f((unsigned short)val[7]);
        }
        *(float4*)(&sv[row][c8])     = lo;
        *(float4*)(&sv[row][c8 + 4]) = hi;
    }
    #pragma unroll
    for (int q = 0; q < 2; ++q) {
        int idx = tid + q * 256;
        int u   = idx >> 3;
        int c4  = (idx & 7) * 4;
        *(float4*)(&sh[u][c4]) = *(const float4*)(hflt + (size_t)u * DD + c0 + c4);
    }
    __syncthreads();

    const int tx = tid & 31;
    const int ty = tid >> 5;
    const int R0 = 64 + ty * 8;

    float acc[8] = {};
    #pragma unroll
    for (int m = 0; m < 8; ++m) {
        float W[15];
        #pragma unroll
        for (int p = 0; p < 15; ++p) W[p] = sv[R0 - 8 * m - 7 + p][tx];
        float h8[8];
        #pragma unroll
        for (int du = 0; du < 8; ++du) h8[du] = sh[8 * m + du][tx];
        #pragma unroll
        for (int du = 0; du < 8; ++du)
            #pragma unroll
            for (int j = 0; j < 8; ++j)
                acc[j] += h8[du] * W[7 + j - du];
    }

    unsigned short* yb = y + ((size_t)b * LL + t0) * DD + c0;
    #pragma unroll
    for (int j = 0; j < 8; ++j) yb[(size_t)(ty * 8 + j) * DD + tx] = f2bf(acc[j]);
}

// ---------------------------------------------------------------------------
// Round-10 tri-buffer GEMM (row-contiguous epilogue) with bf16 intermediates.
// EPI 0: f32 store (out_proj)
// EPI 3: bf16 gate-epi: out = vconv(bf16) * xc(bf16,=A) * sigmoid(acc+b)
// EPI 4: split: col<1024 -> bf16 V; else bf16 ctrl (ldc 2048).
//        EPI4 also uses a supertile block mapping (4by x 6bx chunks per XCD,
//        working set 3.5MB <= 4MB L2) to cut the measured 3.7x A/B over-fetch.
// ---------------------------------------------------------------------------
template <int EPI>
__global__ __launch_bounds__(512, 1) void gemm8p_kernel(
    const unsigned short* __restrict__ A,    // M x 1024
    const unsigned short* __restrict__ BT,   // N x 1024
    const float* __restrict__ bias,          // N
    const unsigned short* __restrict__ vconv,// M x 1024 bf16 (EPI 3)
    void* __restrict__ Cout,
    int Nblk,
    void* __restrict__ Cout2)
{
    constexpr int BUFB = 49152;              // A 32KB (4 chunks) + B 16KB (2 chunks)
    __shared__ char lds[3 * BUFB];

    const int tid  = threadIdx.x;
    const int wave = tid >> 6;
    const int lane = tid & 63;

    const int nwg  = gridDim.x;
    const int orig = blockIdx.x;
    int by, bx;
    if constexpr (EPI == 4) {
        // supertile mapping within each XCD's 4by x 24bx strip: 4x6 chunks
        const int xcd   = orig & 7;
        const int l     = orig >> 3;         // 0..95
        const int chunk = l / 24;            // 0..3
        const int lc    = l % 24;
        by = xcd * 4 + (lc & 3);
        bx = chunk * 6 + (lc >> 2);
    } else {
        const int wg = (orig & 7) * (nwg >> 3) + (orig >> 3);
        by = wg / Nblk;
        bx = wg % Nblk;
    }

    const int wm  = (wave >> 1) * 64;        // 4 waves along M
    const int wn  = (wave & 1) * 64;         // 2 waves along N
    const int llo = lane & 15;
    const int lhi = lane >> 4;

    // ---- staging (pre-swizzled slot within each 64B chunk-row) ----
    const int srow = tid >> 2;               // 0..127 (chunk row)
    const int csl  = tid & 3;
    const int csrc = csl ^ ((srow >> 1) & 3);
    const unsigned short* Asrc = A  + (size_t)(by * 256 + srow) * 1024 + csrc * 8;
    const unsigned short* Bsrc = BT + (size_t)(bx * 128 + srow) * 1024 + csrc * 8;
    char* ldsp = (char*)lds;
    const int wofs = wave * 1024;            // wave-uniform dest base within chunk

    // ---- ds_read offsets (kk=0; kk=1 adds 8192) ----
    const int slot = lhi ^ ((llo >> 1) & 3);
    int offA[4], offB[4];
    #pragma unroll
    for (int mi = 0; mi < 4; ++mi) {
        int rowA = wm + mi * 16 + llo;       // 0..255
        offA[mi] = (rowA >> 7) * 16384 + (rowA & 127) * 64 + slot * 16;
    }
    #pragma unroll
    for (int ni = 0; ni < 4; ++ni) {
        int rowB = wn + ni * 16 + llo;       // 0..127
        offB[ni] = 32768 + rowB * 64 + slot * 16;
    }

    f32x4 acc[4][4] = {};

    // prologue: tile 0 -> buf0, tile 1 -> buf1 (12 loads); wait for tile 0
    {
        gl_lds16(Asrc,                        ldsp + 0 + wofs);
        gl_lds16(Asrc + 32,                   ldsp + 8192 + wofs);
        gl_lds16(Asrc + (size_t)128 * 1024,       ldsp + 16384 + wofs);
        gl_lds16(Asrc + (size_t)128 * 1024 + 32,  ldsp + 24576 + wofs);
        gl_lds16(Bsrc,                        ldsp + 32768 + wofs);
        gl_lds16(Bsrc + 32,                   ldsp + 40960 + wofs);
        gl_lds16(Asrc + 64,                   ldsp + BUFB + 0 + wofs);
        gl_lds16(Asrc + 96,                   ldsp + BUFB + 8192 + wofs);
        gl_lds16(Asrc + (size_t)128 * 1024 + 64,  ldsp + BUFB + 16384 + wofs);
        gl_lds16(Asrc + (size_t)128 * 1024 + 96,  ldsp + BUFB + 24576 + wofs);
        gl_lds16(Bsrc + 64,                   ldsp + BUFB + 32768 + wofs);
        gl_lds16(Bsrc + 96,                   ldsp + BUFB + 40960 + wofs);
    }
    asm volatile("s_waitcnt vmcnt(6)" ::: "memory");
    __builtin_amdgcn_sched_barrier(0);
    __builtin_amdgcn_s_barrier();
    __builtin_amdgcn_sched_barrier(0);

    int bcur = 0;
    for (int t = 0; t < 16; ++t) {
        const int bo  = bcur * BUFB;
        const int nb  = (bcur + 2 >= 3) ? bcur - 1 : bcur + 2;
        const int bo2 = nb * BUFB;
        const int k2  = (t + 2) * 64;
        const bool st = (t < 14);

        // ---- phase 0: kk = 0 ----
        bf16x8 a0 = *(const bf16x8*)(ldsp + bo + offA[0]);
        bf16x8 a1 = *(const bf16x8*)(ldsp + bo + offA[1]);
        bf16x8 a2 = *(const bf16x8*)(ldsp + bo + offA[2]);
        bf16x8 a3 = *(const bf16x8*)(ldsp + bo + offA[3]);
        bf16x8 b0 = *(const bf16x8*)(ldsp + bo + offB[0]);
        bf16x8 b1 = *(const bf16x8*)(ldsp + bo + offB[1]);
        bf16x8 b2 = *(const bf16x8*)(ldsp + bo + offB[2]);
        bf16x8 b3 = *(const bf16x8*)(ldsp + bo + offB[3]);
        if (st) {   // stage t+2: A rows 0-127
            gl_lds16(Asrc + k2,      ldsp + bo2 + 0 + wofs);
            gl_lds16(Asrc + 32 + k2, ldsp + bo2 + 8192 + wofs);
        }
        __builtin_amdgcn_s_barrier();
        __builtin_amdgcn_s_setprio(1);
        acc[0][0] = __builtin_amdgcn_mfma_f32_16x16x32_bf16(a0, b0, acc[0][0], 0, 0, 0);
        acc[0][1] = __builtin_amdgcn_mfma_f32_16x16x32_bf16(a0, b1, acc[0][1], 0, 0, 0);
        acc[0][2] = __builtin_amdgcn_mfma_f32_16x16x32_bf16(a0, b2, acc[0][2], 0, 0, 0);
        acc[0][3] = __builtin_amdgcn_mfma_f32_16x16x32_bf16(a0, b3, acc[0][3], 0, 0, 0);
        acc[1][0] = __builtin_amdgcn_mfma_f32_16x16x32_bf16(a1, b0, acc[1][0], 0, 0, 0);
        acc[1][1] = __builtin_amdgcn_mfma_f32_16x16x32_bf16(a1, b1, acc[1][1], 0, 0, 0);
        acc[1][2] = __builtin_amdgcn_mfma_f32_16x16x32_bf16(a1, b2, acc[1][2], 0, 0, 0);
        acc[1][3] = __builtin_amdgcn_mfma_f32_16x16x32_bf16(a1, b3, acc[1][3], 0, 0, 0);
        acc[2][0] = __builtin_amdgcn_mfma_f32_16x16x32_bf16(a2, b0, acc[2][0], 0, 0, 0);
        acc[2][1] = __builtin_amdgcn_mfma_f32_16x16x32_bf16(a2, b1, acc[2][1], 0, 0, 0);
        acc[2][2] = __builtin_amdgcn_mfma_f32_16x16x32_bf16(a2, b2, acc[2][2], 0, 0, 0);
        acc[2][3] = __builtin_amdgcn_mfma_f32_16x16x32_bf16(a2, b3, acc[2][3], 0, 0, 0);
        acc[3][0] = __builtin_amdgcn_mfma_f32_16x16x32_bf16(a3, b0, acc[3][0], 0, 0, 0);
        acc[3][1] = __builtin_amdgcn_mfma_f32_16x16x32_bf16(a3, b1, acc[3][1], 0, 0, 0);
        acc[3][2] = __builtin_amdgcn_mfma_f32_16x16x32_bf16(a3, b2, acc[3][2], 0, 0, 0);
        acc[3][3] = __builtin_amdgcn_mfma_f32_16x16x32_bf16(a3, b3, acc[3][3], 0, 0, 0);
        __builtin_amdgcn_s_setprio(0);

        // ---- phase 1: kk = 1 ----
        a0 = *(const bf16x8*)(ldsp + bo + offA[0] + 8192);
        a1 = *(const bf16x8*)(ldsp + bo + offA[1] + 8192);
        a2 = *(const bf16x8*)(ldsp + bo + offA[2] + 8192);
        a3 = *(const bf16x8*)(ldsp + bo + offA[3] + 8192);
        b0 = *(const bf16x8*)(ldsp + bo + offB[0] + 8192);
        b1 = *(const bf16x8*)(ldsp + bo + offB[1] + 8192);
        b2 = *(const bf16x8*)(ldsp + bo + offB[2] + 8192);
        b3 = *(const bf16x8*)(ldsp + bo + offB[3] + 8192);
        if (st) {   // stage t+2: A rows 128-255 + B
            gl_lds16(Asrc + (size_t)128 * 1024 + k2,      ldsp + bo2 + 16384 + wofs);
            gl_lds16(Asrc + (size_t)128 * 1024 + 32 + k2, ldsp + bo2 + 24576 + wofs);
            gl_lds16(Bsrc + k2,      ldsp + bo2 + 32768 + wofs);
            gl_lds16(Bsrc + 32 + k2, ldsp + bo2 + 40960 + wofs);
        }
        __builtin_amdgcn_s_barrier();
        __builtin_amdgcn_s_setprio(1);
        acc[0][0] = __builtin_amdgcn_mfma_f32_16x16x32_bf16(a0, b0, acc[0][0], 0, 0, 0);
        acc[0][1] = __builtin_amdgcn_mfma_f32_16x16x32_bf16(a0, b1, acc[0][1], 0, 0, 0);
        acc[0][2] = __builtin_amdgcn_mfma_f32_16x16x32_bf16(a0, b2, acc[0][2], 0, 0, 0);
        acc[0][3] = __builtin_amdgcn_mfma_f32_16x16x32_bf16(a0, b3, acc[0][3], 0, 0, 0);
        acc[1][0] = __builtin_amdgcn_mfma_f32_16x16x32_bf16(a1, b0, acc[1][0], 0, 0, 0);
        acc[1][1] = __builtin_amdgcn_mfma_f32_16x16x32_bf16(a1, b1, acc[1][1], 0, 0, 0);
        acc[1][2] = __builtin_amdgcn_mfma_f32_16x16x32_bf16(a1, b2, acc[1][2], 0, 0, 0);
        acc[1][3] = __builtin_amdgcn_mfma_f32_16x16x32_bf16(a1, b3, acc[1][3], 0, 0, 0);
        acc[2][0] = __builtin_amdgcn_mfma_f32_16x16x32_bf16(a2, b0, acc[2][0], 0, 0, 0);
        acc[2][1] = __builtin_amdgcn_mfma_f32_16x16x32_bf16(a2, b1, acc[2][1], 0, 0, 0);
        acc[2][2] = __builtin_amdgcn_mfma_f32_16x16x32_bf16(a2, b2, acc[2][2], 0, 0, 0);
        acc[2][3] = __builtin_amdgcn_mfma_f32_16x16x32_bf16(a2, b3, acc[2][3], 0, 0, 0);
        acc[3][0] = __builtin_amdgcn_mfma_f32_16x16x32_bf16(a3, b0, acc[3][0], 0, 0, 0);
        acc[3][1] = __builtin_amdgcn_mfma_f32_16x16x32_bf16(a3, b1, acc[3][1], 0, 0, 0);
        acc[3][2] = __builtin_amdgcn_mfma_f32_16x16x32_bf16(a3, b2, acc[3][2], 0, 0, 0);
        acc[3][3] = __builtin_amdgcn_mfma_f32_16x16x32_bf16(a3, b3, acc[3][3], 0, 0, 0);
        __builtin_amdgcn_s_setprio(0);

        // ---- tile end: tile t+1 landed; t+2 stays in flight ----
        if (st)           asm volatile("s_waitcnt vmcnt(6)" ::: "memory");
        else if (t == 14) asm volatile("s_waitcnt vmcnt(0)" ::: "memory");
        if (t < 15) {
            __builtin_amdgcn_s_barrier();
            __builtin_amdgcn_sched_barrier(0);
        }
        bcur = (bcur + 1 >= 3) ? 0 : bcur + 1;
    }

    // ---- epilogue, row-contiguous order: mi { r { ni } } ----
    float bj[4];
    #pragma unroll
    for (int ni = 0; ni < 4; ++ni) bj[ni] = bias[bx * 128 + wn + ni * 16 + llo];
    #pragma unroll
    for (int mi = 0; mi < 4; ++mi) {
        #pragma unroll
        for (int r = 0; r < 4; ++r) {
            const int rowg = by * 256 + wm + mi * 16 + lhi * 4 + r;
            #pragma unroll
            for (int ni = 0; ni < 4; ++ni) {
                const int col = bx * 128 + wn + ni * 16 + llo;
                float v = acc[mi][ni][r] + bj[ni];
                if (EPI == 0) {
                    ((float*)Cout)[(size_t)rowg * 1024 + col] = v;
                } else if (EPI == 4) {
                    if (col < 1024) ((unsigned short*)Cout)[(size_t)rowg * 1024 + col] = f2bf(v);
                    else ((unsigned short*)Cout2)[(size_t)rowg * 2048 + (col - 1024)] = f2bf(v);
                } else {
                    float xc = bf2f(A[(size_t)rowg * 1024 + col]);
                    float vc = bf2f(vconv[(size_t)rowg * 1024 + col]);
                    float o  = vc * xc * (1.0f / (1.0f + expf(-v)));
                    ((unsigned short*)Cout)[(size_t)rowg * 1024 + col] = f2bf(o);
                }
            }
        }
    }
}

// ---------------------------------------------------------------------------
extern "C" void kernel_launch(void* const* d_in, const int* in_sizes, int n_in,
                              void* d_out, int out_size, void* d_ws, size_t ws_size,
                              hipStream_t stream) {
    const float* x     = (const float*)d_in[0];
    const float* ipw   = (const float*)d_in[1];
    const float* ipb   = (const float*)d_in[2];
    const float* opw   = (const float*)d_in[3];
    const float* opb   = (const float*)d_in[4];
    const float* freqs = (const float*)d_in[5];
    const float* w1    = (const float*)d_in[6];
    const float* b1    = (const float*)d_in[7];
    const float* w2    = (const float*)d_in[8];
    const float* b2    = (const float*)d_in[9];
    const float* w3    = (const float*)d_in[10];
    const float* b3    = (const float*)d_in[11];
    const float* decay = (const float*)d_in[12];
    const float* cw    = (const float*)d_in[13];
    const float* cb    = (const float*)d_in[14];
    const float* gw    = (const float*)d_in[15];
    const float* gb    = (const float*)d_in[16];
    float* out = (float*)d_out;

    // workspace layout
    char* w = (char*)d_ws;
    float* h             = (float*)w;                                // NORD*TAPS*DD f32
    unsigned short* ipwT = (unsigned short*)(w + (size_t)1048576);   // 3072x1024 bf16
    unsigned short* gw0T = ipwT + (size_t)3072 * 1024;               // 1024x1024
    unsigned short* gw1T = gw0T + (size_t)1024 * 1024;
    unsigned short* opwT = gw1T + (size_t)1024 * 1024;
    unsigned short* xb   = opwT + (size_t)1024 * 1024;               // 8192x1024 bf16 (x, later v2)
    unsigned short* V    = xb + (size_t)8192 * 1024;                 // 8192x1024 bf16 (v0, v1)
    unsigned short* ctrlB= V + (size_t)8192 * 1024;                  // 8192x2048 bf16
    unsigned short* xcB  = ctrlB + (size_t)8192 * 2048;              // 8192x1024 bf16
    unsigned short* vconv= (unsigned short*)out;                     // d_out as bf16 scratch

    dim3 blk(256);
    dim3 blk512(512);

    // prep: cvt + 4 weight transposes + implicit filters (one dispatch)
    prep_kernel<<<10368, blk, 0, stream>>>(x, xb, ipw, ipwT, gw, gw0T, gw1T,
                                           opw, opwT, freqs, w1, b1, w2, b2, w3, b3, decay, h);

    // fused in_proj: cols<1024 -> V (bf16), cols>=1024 -> ctrlB (bf16)
    gemm8p_kernel<4><<<768, blk512, 0, stream>>>(xb, ipwT, ipb, nullptr, V, 24, ctrlB);

    // order 0: conv(V)->vconv  ||  dwconv(ctrl0)->xcB, then gate GEMM -> V
    convdw_kernel<<<8192, blk, 0, stream>>>(V, h, vconv, ctrlB, 2048, cw, cb, xcB);
    gemm8p_kernel<3><<<256, blk512, 0, stream>>>(xcB, gw0T, gb, vconv, V, 8, nullptr);

    // order 1
    convdw_kernel<<<8192, blk, 0, stream>>>(V, h + (size_t)TAPS * DD, vconv,
                                            ctrlB + 1024, 2048, cw + (size_t)KW * DD, cb + DD, xcB);
    gemm8p_kernel<3><<<256, blk512, 0, stream>>>(xcB, gw1T, gb + DD, vconv, xb, 8, nullptr);

    // out = v2 @ opw + opb
    gemm8p_kernel<0><<<256, blk512, 0, stream>>>(xb, opwT, opb, nullptr, out, 8, nullptr);
}